// Round 11
// baseline (223.223 us; speedup 1.0000x reference)
//
#include <hip/hip_runtime.h>

typedef float f32x4 __attribute__((ext_vector_type(4)));
typedef short short8 __attribute__((ext_vector_type(8)));

#define GBL(p) ((__attribute__((address_space(1))) void*)(p))
#define LDS(p) ((__attribute__((address_space(3))) void*)(p))

static __device__ __forceinline__ unsigned short f2bf(float x) {
  union { float f; unsigned u; } a; a.f = x;
  unsigned u = a.u;
  return (unsigned short)((u + 0x7FFFu + ((u >> 16) & 1u)) >> 16);
}

static __device__ __forceinline__ short8 ld8(const unsigned short* p) {
  return *(const short8*)(p);
}

static __device__ __forceinline__ f32x4 zero4() {
  f32x4 z = {0.f, 0.f, 0.f, 0.f};
  return z;
}

// ---------------- fused fp32 -> bf16 convert (x, W_qkv, W_out) ----------------
__global__ void cvt3_kernel(const float4* __restrict__ x,    ushort4* __restrict__ xo,
                            const float4* __restrict__ wq,   ushort4* __restrict__ wqo,
                            const float4* __restrict__ wo,   ushort4* __restrict__ woo) {
  int i = blockIdx.x * blockDim.x + threadIdx.x;
  const float4* in; ushort4* out; int j;
  if (i < 1048576)      { in = x;  out = xo;  j = i; }
  else if (i < 1835008) { in = wq; out = wqo; j = i - 1048576; }
  else                  { in = wo; out = woo; j = i - 1835008; }
  float4 v = in[j];
  ushort4 o;
  o.x = f2bf(v.x); o.y = f2bf(v.y); o.z = f2bf(v.z); o.w = f2bf(v.w);
  out[j] = o;
}

// ---------------- GEMM1: qkv = x * Wqkv^T, split epilogue ----------------
//   col <1024  -> Q bf16 [4096][1024], PRE-SCALED by 0.125*log2(e)  (Cout)
//   col <2048  -> K fragment-linear: block(bh,t16,c) of 1KB (Cout2)
//   col >=2048 -> V fragment-linear: block(bh,t32,nd) of 1KB (Cout3)
__global__ __launch_bounds__(256) void gemm_qkv(
    const unsigned short* __restrict__ A,
    const unsigned short* __restrict__ B,
    void* __restrict__ Cout, void* __restrict__ Cout2, void* __restrict__ Cout3,
    int M, int N, int K)
{
  __shared__ __align__(16) unsigned short As[128 * 32];
  __shared__ __align__(16) unsigned short Bs[128 * 32];

  const int t = threadIdx.x;
  const int lane = t & 63;
  const int w = t >> 6;
  const int wr = (w >> 1) * 64;
  const int wc = (w & 1) * 64;
  const int fr = lane & 15;
  const int kg = lane >> 4;

  // XCD-aware bijective swizzle (nwg = 24*32 = 768, 768%8==0)
  const int lin = blockIdx.y * gridDim.x + blockIdx.x;
  const int cpx = (gridDim.x * gridDim.y) >> 3;
  const int l2 = (lin & 7) * cpx + (lin >> 3);
  const int bx = l2 % gridDim.x, by = l2 / gridDim.x;
  const size_t rowBase = (size_t)by * 128;
  const size_t colBase = (size_t)bx * 128;

  f32x4 acc[4][4];
  for (int m = 0; m < 4; ++m)
    for (int n = 0; n < 4; ++n) acc[m][n] = zero4();

  const unsigned short* ag = A + (rowBase + (t >> 2)) * (size_t)K + (t & 3) * 8;
  const unsigned short* bg = B + (colBase + (t >> 2)) * (size_t)K + (t & 3) * 8;
  unsigned short* asd = As + t * 8;
  unsigned short* bsd = Bs + t * 8;

  for (int k0 = 0; k0 < K; k0 += 32) {
    __builtin_amdgcn_global_load_lds(GBL(ag + k0),                   LDS(asd),        16, 0, 0);
    __builtin_amdgcn_global_load_lds(GBL(ag + (size_t)64 * K + k0),  LDS(asd + 2048), 16, 0, 0);
    __builtin_amdgcn_global_load_lds(GBL(bg + k0),                   LDS(bsd),        16, 0, 0);
    __builtin_amdgcn_global_load_lds(GBL(bg + (size_t)64 * K + k0),  LDS(bsd + 2048), 16, 0, 0);
    __syncthreads();
    short8 af[4], bf[4];
    for (int m = 0; m < 4; ++m) af[m] = ld8(As + (wr + m * 16 + fr) * 32 + kg * 8);
    for (int n = 0; n < 4; ++n) bf[n] = ld8(Bs + (wc + n * 16 + fr) * 32 + kg * 8);
    for (int m = 0; m < 4; ++m)
      for (int n = 0; n < 4; ++n)
        acc[m][n] = __builtin_amdgcn_mfma_f32_16x16x32_bf16(af[m], bf[n], acc[m][n], 0, 0, 0);
    __syncthreads();
  }

  for (int m = 0; m < 4; ++m)
    for (int n = 0; n < 4; ++n) {
      const size_t row = rowBase + wr + m * 16 + kg * 4;
      const size_t col = colBase + wc + n * 16 + fr;
      if (col < 1024) {
        unsigned short* Q = (unsigned short*)Cout;       // [4096][1024], prescaled
        for (int j = 0; j < 4; ++j)
          Q[(row + j) * 1024 + col] = f2bf(acc[m][n][j] * 0.18033688f);
      } else if (col < 2048) {
        unsigned short* KF = (unsigned short*)Cout2;
        const int d_all = (int)col - 1024;
        const int hh = d_all >> 6, d = d_all & 63;
        const int c = d >> 5, kgp = (d >> 3) & 3, el = d & 7;
        for (int j = 0; j < 4; ++j) {
          const int r = (int)row + j;
          const int bp = r >> 11, s = r & 2047;
          const size_t addr =
              ((size_t)(((bp * 16 + hh) * 128 + (s >> 4)) * 2 + c)) * 512
              + (size_t)((kgp * 16 + (s & 15)) * 8 + el);
          KF[addr] = f2bf(acc[m][n][j]);
        }
      } else {
        unsigned short* VF = (unsigned short*)Cout3;
        const int d_all = (int)col - 2048;
        const int hh = d_all >> 6, dd = d_all & 63;
        const int nd = dd >> 4, frp = dd & 15;
        const int r0 = (int)row;
        const int bp = r0 >> 11, s = r0 & 2047;
        const size_t base =
            ((size_t)(((bp * 16 + hh) * 64 + (s >> 5)) * 4 + nd)) * 512
            + (size_t)((((s >> 3) & 3) * 16 + frp) * 8 + (s & 7));
        ushort4 o4;
        o4.x = f2bf(acc[m][n][0]); o4.y = f2bf(acc[m][n][1]);
        o4.z = f2bf(acc[m][n][2]); o4.w = f2bf(acc[m][n][3]);
        *(ushort4*)(VF + base) = o4;
      }
    }
}

// ---------------- GEMM2: out = attno * Wout^T, 64x128 tile (2 blocks/CU) ----------------
__global__ __launch_bounds__(256) void gemm_out(
    const unsigned short* __restrict__ A,
    const unsigned short* __restrict__ B,
    float* __restrict__ C, int M, int N, int K)
{
  __shared__ __align__(16) unsigned short As[64 * 32];
  __shared__ __align__(16) unsigned short Bs[128 * 32];

  const int t = threadIdx.x;
  const int lane = t & 63;
  const int w = t >> 6;
  const int wr = (w >> 1) * 32;
  const int wc = (w & 1) * 64;
  const int fr = lane & 15;
  const int kg = lane >> 4;

  // XCD-aware bijective swizzle (nwg = 8*64 = 512, 512%8==0)
  const int lin = blockIdx.y * gridDim.x + blockIdx.x;
  const int cpx = (gridDim.x * gridDim.y) >> 3;
  const int l2 = (lin & 7) * cpx + (lin >> 3);
  const int bx = l2 % gridDim.x, by = l2 / gridDim.x;
  const size_t rowBase = (size_t)by * 64;
  const size_t colBase = (size_t)bx * 128;

  f32x4 acc[2][4];
  for (int m = 0; m < 2; ++m)
    for (int n = 0; n < 4; ++n) acc[m][n] = zero4();

  const unsigned short* ag = A + (rowBase + (t >> 2)) * (size_t)K + (t & 3) * 8;
  const unsigned short* bg = B + (colBase + (t >> 2)) * (size_t)K + (t & 3) * 8;
  unsigned short* asd = As + t * 8;
  unsigned short* bsd = Bs + t * 8;

  for (int k0 = 0; k0 < K; k0 += 32) {
    __builtin_amdgcn_global_load_lds(GBL(ag + k0),                   LDS(asd),        16, 0, 0);
    __builtin_amdgcn_global_load_lds(GBL(bg + k0),                   LDS(bsd),        16, 0, 0);
    __builtin_amdgcn_global_load_lds(GBL(bg + (size_t)64 * K + k0),  LDS(bsd + 2048), 16, 0, 0);
    __syncthreads();
    short8 af[2], bf[4];
    for (int m = 0; m < 2; ++m) af[m] = ld8(As + (wr + m * 16 + fr) * 32 + kg * 8);
    for (int n = 0; n < 4; ++n) bf[n] = ld8(Bs + (wc + n * 16 + fr) * 32 + kg * 8);
    for (int m = 0; m < 2; ++m)
      for (int n = 0; n < 4; ++n)
        acc[m][n] = __builtin_amdgcn_mfma_f32_16x16x32_bf16(af[m], bf[n], acc[m][n], 0, 0, 0);
    __syncthreads();
  }

  for (int m = 0; m < 2; ++m)
    for (int n = 0; n < 4; ++n) {
      const size_t row = rowBase + wr + m * 16 + kg * 4;
      const size_t col = colBase + wc + n * 16 + fr;
      for (int j = 0; j < 4; ++j) C[(row + j) * N + col] = acc[m][n][j];
    }
}

// ---------------- causal flash attention ----------------
// Fragment-linear K/V, mask-free main loop, cross-tile P pipeline,
// 1024 blocks longest-first (4 blocks/CU).
// Softmax internals = Round-6-verified formulation (exp2f + f2bf stores).
__global__ __launch_bounds__(256, 4) void attn_kernel(
    const unsigned short* __restrict__ qb,
    const unsigned short* __restrict__ kfb,
    const unsigned short* __restrict__ vfb,
    unsigned short* __restrict__ om)
{
  __shared__ __align__(16) unsigned short Ps[4][16 * 32];

  const int bh = blockIdx.x;
  const int qt = 31 - blockIdx.y;     // longest blocks dispatched first
  const int b = bh >> 4, h = bh & 15;
  const int t = threadIdx.x;
  const int lane = t & 63, w = t >> 6;
  const int fr = lane & 15, kg = lane >> 4;
  const int lane8 = lane * 8;
  const size_t seq0 = (size_t)b * 2048;

  unsigned short* pw = &Ps[w][0];
  const unsigned short* kfB = kfb + (size_t)bh * (128 * 2 * 512) + lane8;
  const unsigned short* vfB = vfb + (size_t)bh * (64 * 4 * 512) + lane8;

  // Hoisted P-store addresses (loop-invariant)
  unsigned short* pws0[4];
  unsigned short* pws1[4];
#pragma unroll
  for (int j = 0; j < 4; ++j) {
    const int r = kg * 4 + j;
    pws0[j] = pw + r * 32 + ((((fr >> 3)       ^ kg) & 3) << 3) + (fr & 7);
    pws1[j] = pw + r * 32 + ((((2 + (fr >> 3)) ^ kg) & 3) << 3) + (fr & 7);
  }
  const int rdswz = fr * 32 + (((kg ^ (fr >> 2)) & 3) << 3);

#define LOADK(kr0, kf) do {                                                    \
    const unsigned short* kp = kfB + (size_t)((kr0) >> 4) * 1024;              \
    kf[0] = ld8(kp);        kf[1] = ld8(kp + 512);                             \
    kf[2] = ld8(kp + 1024); kf[3] = ld8(kp + 1536);                            \
  } while (0)

#define LOADV(kr0, vf) do {                                                    \
    const unsigned short* vp = vfB + (size_t)((kr0) >> 5) * 2048;              \
    vf[0] = ld8(vp);        vf[1] = ld8(vp + 512);                             \
    vf[2] = ld8(vp + 1024); vf[3] = ld8(vp + 1536);                            \
  } while (0)

#define QKSM(kr0, kf, DOMASK) do {                                             \
    f32x4 s0 = zero4(), s1 = zero4();                                          \
    __builtin_amdgcn_s_setprio(1);                                             \
    s0 = __builtin_amdgcn_mfma_f32_16x16x32_bf16(qf0, kf[0], s0, 0, 0, 0);     \
    s0 = __builtin_amdgcn_mfma_f32_16x16x32_bf16(qf1, kf[1], s0, 0, 0, 0);     \
    s1 = __builtin_amdgcn_mfma_f32_16x16x32_bf16(qf0, kf[2], s1, 0, 0, 0);     \
    s1 = __builtin_amdgcn_mfma_f32_16x16x32_bf16(qf1, kf[3], s1, 0, 0, 0);     \
    __builtin_amdgcn_s_setprio(0);                                             \
    _Pragma("unroll")                                                          \
    for (int j = 0; j < 4; ++j) {                                              \
      float a0 = s0[j];                                                        \
      float a1 = s1[j];                                                        \
      if (DOMASK) {                                                            \
        const int qrow = qrow0 + kg * 4 + j;                                   \
        a0 = ((kr0) + fr      <= qrow) ? a0 : -1e30f;                          \
        a1 = ((kr0) + 16 + fr <= qrow) ? a1 : -1e30f;                          \
      }                                                                        \
      const float e0 = exp2f(a0);                                              \
      const float e1 = exp2f(a1);                                              \
      l_run[j] += e0 + e1;                                                     \
      *pws0[j] = f2bf(e0);                                                     \
      *pws1[j] = f2bf(e1);                                                     \
    }                                                                          \
  } while (0)

#define PV(vf) do {                                                            \
    __builtin_amdgcn_s_setprio(1);                                             \
    _Pragma("unroll")                                                          \
    for (int nd = 0; nd < 4; ++nd)                                             \
      o[nd] = __builtin_amdgcn_mfma_f32_16x16x32_bf16(pf, vf[nd], o[nd], 0, 0, 0); \
    __builtin_amdgcn_s_setprio(0);                                             \
  } while (0)

#define READP do { pf = ld8(pw + rdswz); } while (0)

  {
    const int qrow0 = qt * 64 + w * 16;
    const int nfull = qrow0 >> 5;       // fully-unmasked 32-k tiles; diagonal tile = nfull

    const unsigned short* qp = qb + (seq0 + qrow0 + fr) * 1024 + h * 64;
    const short8 qf0 = ld8(qp + kg * 8);
    const short8 qf1 = ld8(qp + 32 + kg * 8);

    float l_run[4] = {0.f, 0.f, 0.f, 0.f};
    f32x4 o[4];
    for (int n = 0; n < 4; ++n) o[n] = zero4();

    short8 kA[4], kB[4], vA[4], vB[4], pf;
    LOADK(0, kA);
    int kt = 0;
    while (true) {
      {   // even phase: K in kA; V(kt)->vA; PV(prev) from vB
        const int kn = (kt < nfull) ? (kt + 1) * 32 : nfull * 32;
        LOADK(kn, kB);
        LOADV(kt * 32, vA);
        if (kt == nfull) { QKSM(kt * 32, kA, 1); } else { QKSM(kt * 32, kA, 0); }
        if (kt > 0) PV(vB);
        READP;
      }
      if (kt == nfull) { PV(vA); break; }
      ++kt;
      {   // odd phase: K in kB; V(kt)->vB; PV(prev) from vA
        const int kn = (kt < nfull) ? (kt + 1) * 32 : nfull * 32;
        LOADK(kn, kA);
        LOADV(kt * 32, vB);
        if (kt == nfull) { QKSM(kt * 32, kB, 1); } else { QKSM(kt * 32, kB, 0); }
        PV(vA);
        READP;
      }
      if (kt == nfull) { PV(vB); break; }
      ++kt;
    }

    for (int j = 0; j < 4; ++j) {
      float l = l_run[j];
      l += __shfl_xor(l, 1);
      l += __shfl_xor(l, 2);
      l += __shfl_xor(l, 4);
      l += __shfl_xor(l, 8);
      const float inv = 1.0f / l;
      for (int nd = 0; nd < 4; ++nd) {
        om[(seq0 + qrow0 + kg * 4 + j) * 1024 + h * 64 + nd * 16 + fr] =
            f2bf(o[nd][j] * inv);
      }
    }
  }
#undef LOADK
#undef LOADV
#undef QKSM
#undef PV
#undef READP
}

// ---------------- launch ----------------
extern "C" void kernel_launch(void* const* d_in, const int* in_sizes, int n_in,
                              void* d_out, int out_size, void* d_ws, size_t ws_size,
                              hipStream_t stream) {
  const float* x    = (const float*)d_in[0];   // [2,2048,1024]
  const float* Wqkv = (const float*)d_in[1];   // [3072,1024]
  const float* Wout = (const float*)d_in[2];   // [1024,1024]
  float* out = (float*)d_out;                  // [2,2048,1024]

  char* ws = (char*)d_ws;
  unsigned short* xb    = (unsigned short*)(ws);                      //  8 MB  [4096][1024]
  unsigned short* wqkvb = (unsigned short*)(ws + 8388608);            //  6 MB  [3072][1024]
  unsigned short* woutb = (unsigned short*)(ws + 14680064);           //  2 MB  [1024][1024]
  unsigned short* qbuf  = (unsigned short*)(ws + 16777216);           //  8 MB  [4096][1024]
  unsigned short* kfb   = (unsigned short*)(ws + 25165824);           //  8 MB  fragment-linear K
  unsigned short* vfb   = (unsigned short*)(ws + 33554432);           //  8 MB  fragment-linear V
  unsigned short* attno = (unsigned short*)(ws + 41943040);           //  8 MB  [4096][1024]

  cvt3_kernel<<<dim3(8192), dim3(256), 0, stream>>>(
      (const float4*)x,    (ushort4*)xb,
      (const float4*)Wqkv, (ushort4*)wqkvb,
      (const float4*)Wout, (ushort4*)woutb);

  gemm_qkv<<<dim3(24, 32), dim3(256), 0, stream>>>(
      xb, wqkvb, (void*)qbuf, (void*)kfb, (void*)vfb, 4096, 3072, 1024);

  attn_kernel<<<dim3(32, 32), dim3(256), 0, stream>>>(qbuf, kfb, vfb, attno);

  gemm_out<<<dim3(8, 64), dim3(256), 0, stream>>>(attno, woutb, out, 4096, 1024, 1024);
}

// Round 13
// 181.420 us; speedup vs baseline: 1.2304x; 1.2304x over previous
//
#include <hip/hip_runtime.h>

typedef float f32x4 __attribute__((ext_vector_type(4)));
typedef short short8 __attribute__((ext_vector_type(8)));

#define GBL(p) ((__attribute__((address_space(1))) void*)(p))
#define LDS(p) ((__attribute__((address_space(3))) void*)(p))

static __device__ __forceinline__ unsigned short f2bf(float x) {
  union { float f; unsigned u; } a; a.f = x;
  unsigned u = a.u;
  return (unsigned short)((u + 0x7FFFu + ((u >> 16) & 1u)) >> 16);
}

static __device__ __forceinline__ short8 ld8(const unsigned short* p) {
  return *(const short8*)(p);
}

static __device__ __forceinline__ f32x4 zero4() {
  f32x4 z = {0.f, 0.f, 0.f, 0.f};
  return z;
}

// ---------------- fused fp32 -> bf16 convert (x, W_qkv, W_out) ----------------
__global__ void cvt3_kernel(const float4* __restrict__ x,    ushort4* __restrict__ xo,
                            const float4* __restrict__ wq,   ushort4* __restrict__ wqo,
                            const float4* __restrict__ wo,   ushort4* __restrict__ woo) {
  int i = blockIdx.x * blockDim.x + threadIdx.x;
  const float4* in; ushort4* out; int j;
  if (i < 1048576)      { in = x;  out = xo;  j = i; }
  else if (i < 1835008) { in = wq; out = wqo; j = i - 1048576; }
  else                  { in = wo; out = woo; j = i - 1835008; }
  float4 v = in[j];
  ushort4 o;
  o.x = f2bf(v.x); o.y = f2bf(v.y); o.z = f2bf(v.z); o.w = f2bf(v.w);
  out[j] = o;
}

// ---------------- GEMM1: qkv = x * Wqkv^T, split epilogue ----------------
//   col <1024  -> Q bf16 [4096][1024], PRE-SCALED by 0.125*log2(e)  (Cout)
//   col <2048  -> K fragment-linear: block(bh,t16,c) of 1KB (Cout2)
//   col >=2048 -> V fragment-linear: block(bh,t32,nd) of 1KB (Cout3)
__global__ __launch_bounds__(256) void gemm_qkv(
    const unsigned short* __restrict__ A,
    const unsigned short* __restrict__ B,
    void* __restrict__ Cout, void* __restrict__ Cout2, void* __restrict__ Cout3,
    int M, int N, int K)
{
  __shared__ __align__(16) unsigned short As[128 * 32];
  __shared__ __align__(16) unsigned short Bs[128 * 32];

  const int t = threadIdx.x;
  const int lane = t & 63;
  const int w = t >> 6;
  const int wr = (w >> 1) * 64;
  const int wc = (w & 1) * 64;
  const int fr = lane & 15;
  const int kg = lane >> 4;

  // XCD-aware bijective swizzle (nwg = 24*32 = 768, 768%8==0)
  const int lin = blockIdx.y * gridDim.x + blockIdx.x;
  const int cpx = (gridDim.x * gridDim.y) >> 3;
  const int l2 = (lin & 7) * cpx + (lin >> 3);
  const int bx = l2 % gridDim.x, by = l2 / gridDim.x;
  const size_t rowBase = (size_t)by * 128;
  const size_t colBase = (size_t)bx * 128;

  f32x4 acc[4][4];
  for (int m = 0; m < 4; ++m)
    for (int n = 0; n < 4; ++n) acc[m][n] = zero4();

  const unsigned short* ag = A + (rowBase + (t >> 2)) * (size_t)K + (t & 3) * 8;
  const unsigned short* bg = B + (colBase + (t >> 2)) * (size_t)K + (t & 3) * 8;
  unsigned short* asd = As + t * 8;
  unsigned short* bsd = Bs + t * 8;

  for (int k0 = 0; k0 < K; k0 += 32) {
    __builtin_amdgcn_global_load_lds(GBL(ag + k0),                   LDS(asd),        16, 0, 0);
    __builtin_amdgcn_global_load_lds(GBL(ag + (size_t)64 * K + k0),  LDS(asd + 2048), 16, 0, 0);
    __builtin_amdgcn_global_load_lds(GBL(bg + k0),                   LDS(bsd),        16, 0, 0);
    __builtin_amdgcn_global_load_lds(GBL(bg + (size_t)64 * K + k0),  LDS(bsd + 2048), 16, 0, 0);
    __syncthreads();
    short8 af[4], bf[4];
    for (int m = 0; m < 4; ++m) af[m] = ld8(As + (wr + m * 16 + fr) * 32 + kg * 8);
    for (int n = 0; n < 4; ++n) bf[n] = ld8(Bs + (wc + n * 16 + fr) * 32 + kg * 8);
    for (int m = 0; m < 4; ++m)
      for (int n = 0; n < 4; ++n)
        acc[m][n] = __builtin_amdgcn_mfma_f32_16x16x32_bf16(af[m], bf[n], acc[m][n], 0, 0, 0);
    __syncthreads();
  }

  for (int m = 0; m < 4; ++m)
    for (int n = 0; n < 4; ++n) {
      const size_t row = rowBase + wr + m * 16 + kg * 4;
      const size_t col = colBase + wc + n * 16 + fr;
      if (col < 1024) {
        unsigned short* Q = (unsigned short*)Cout;       // [4096][1024], prescaled
        for (int j = 0; j < 4; ++j)
          Q[(row + j) * 1024 + col] = f2bf(acc[m][n][j] * 0.18033688f);
      } else if (col < 2048) {
        unsigned short* KF = (unsigned short*)Cout2;
        const int d_all = (int)col - 1024;
        const int hh = d_all >> 6, d = d_all & 63;
        const int c = d >> 5, kgp = (d >> 3) & 3, el = d & 7;
        for (int j = 0; j < 4; ++j) {
          const int r = (int)row + j;
          const int bp = r >> 11, s = r & 2047;
          const size_t addr =
              ((size_t)(((bp * 16 + hh) * 128 + (s >> 4)) * 2 + c)) * 512
              + (size_t)((kgp * 16 + (s & 15)) * 8 + el);
          KF[addr] = f2bf(acc[m][n][j]);
        }
      } else {
        unsigned short* VF = (unsigned short*)Cout3;
        const int d_all = (int)col - 2048;
        const int hh = d_all >> 6, dd = d_all & 63;
        const int nd = dd >> 4, frp = dd & 15;
        const int r0 = (int)row;
        const int bp = r0 >> 11, s = r0 & 2047;
        const size_t base =
            ((size_t)(((bp * 16 + hh) * 64 + (s >> 5)) * 4 + nd)) * 512
            + (size_t)((((s >> 3) & 3) * 16 + frp) * 8 + (s & 7));
        ushort4 o4;
        o4.x = f2bf(acc[m][n][0]); o4.y = f2bf(acc[m][n][1]);
        o4.z = f2bf(acc[m][n][2]); o4.w = f2bf(acc[m][n][3]);
        *(ushort4*)(VF + base) = o4;
      }
    }
}

// ---------------- GEMM2: out = attno * Wout^T, 64x128 tile (2 blocks/CU) ----------------
__global__ __launch_bounds__(256) void gemm_out(
    const unsigned short* __restrict__ A,
    const unsigned short* __restrict__ B,
    float* __restrict__ C, int M, int N, int K)
{
  __shared__ __align__(16) unsigned short As[64 * 32];
  __shared__ __align__(16) unsigned short Bs[128 * 32];

  const int t = threadIdx.x;
  const int lane = t & 63;
  const int w = t >> 6;
  const int wr = (w >> 1) * 32;
  const int wc = (w & 1) * 64;
  const int fr = lane & 15;
  const int kg = lane >> 4;

  // XCD-aware bijective swizzle (nwg = 8*64 = 512, 512%8==0)
  const int lin = blockIdx.y * gridDim.x + blockIdx.x;
  const int cpx = (gridDim.x * gridDim.y) >> 3;
  const int l2 = (lin & 7) * cpx + (lin >> 3);
  const int bx = l2 % gridDim.x, by = l2 / gridDim.x;
  const size_t rowBase = (size_t)by * 64;
  const size_t colBase = (size_t)bx * 128;

  f32x4 acc[2][4];
  for (int m = 0; m < 2; ++m)
    for (int n = 0; n < 4; ++n) acc[m][n] = zero4();

  const unsigned short* ag = A + (rowBase + (t >> 2)) * (size_t)K + (t & 3) * 8;
  const unsigned short* bg = B + (colBase + (t >> 2)) * (size_t)K + (t & 3) * 8;
  unsigned short* asd = As + t * 8;
  unsigned short* bsd = Bs + t * 8;

  for (int k0 = 0; k0 < K; k0 += 32) {
    __builtin_amdgcn_global_load_lds(GBL(ag + k0),                   LDS(asd),        16, 0, 0);
    __builtin_amdgcn_global_load_lds(GBL(bg + k0),                   LDS(bsd),        16, 0, 0);
    __builtin_amdgcn_global_load_lds(GBL(bg + (size_t)64 * K + k0),  LDS(bsd + 2048), 16, 0, 0);
    __syncthreads();
    short8 af[2], bf[4];
    for (int m = 0; m < 2; ++m) af[m] = ld8(As + (wr + m * 16 + fr) * 32 + kg * 8);
    for (int n = 0; n < 4; ++n) bf[n] = ld8(Bs + (wc + n * 16 + fr) * 32 + kg * 8);
    for (int m = 0; m < 2; ++m)
      for (int n = 0; n < 4; ++n)
        acc[m][n] = __builtin_amdgcn_mfma_f32_16x16x32_bf16(af[m], bf[n], acc[m][n], 0, 0, 0);
    __syncthreads();
  }

  for (int m = 0; m < 2; ++m)
    for (int n = 0; n < 4; ++n) {
      const size_t row = rowBase + wr + m * 16 + kg * 4;
      const size_t col = colBase + wc + n * 16 + fr;
      for (int j = 0; j < 4; ++j) C[(row + j) * N + col] = acc[m][n][j];
    }
}

// ---------------- causal flash attention ----------------
// Fragment-linear K/V, mask-free main loop, cross-tile P pipeline,
// 1024 blocks longest-first. Plain __launch_bounds__(256): VGPR ~104 (<=128)
// allows 4 waves/SIMD WITHOUT spilling (R11 lesson: (256,4) forced VGPR=64 ->
// 30 MB scratch spill traffic, attn 93us).
__global__ __launch_bounds__(256) void attn_kernel(
    const unsigned short* __restrict__ qb,
    const unsigned short* __restrict__ kfb,
    const unsigned short* __restrict__ vfb,
    unsigned short* __restrict__ om)
{
  __shared__ __align__(16) unsigned short Ps[4][16 * 32];

  const int bh = blockIdx.x;
  const int qt = 31 - blockIdx.y;     // longest blocks dispatched first
  const int b = bh >> 4, h = bh & 15;
  const int t = threadIdx.x;
  const int lane = t & 63, w = t >> 6;
  const int fr = lane & 15, kg = lane >> 4;
  const int lane8 = lane * 8;
  const size_t seq0 = (size_t)b * 2048;

  unsigned short* pw = &Ps[w][0];
  const unsigned short* kfB = kfb + (size_t)bh * (128 * 2 * 512) + lane8;
  const unsigned short* vfB = vfb + (size_t)bh * (64 * 4 * 512) + lane8;

  // Hoisted P-store addresses (loop-invariant)
  unsigned short* pws0[4];
  unsigned short* pws1[4];
#pragma unroll
  for (int j = 0; j < 4; ++j) {
    const int r = kg * 4 + j;
    pws0[j] = pw + r * 32 + ((((fr >> 3)       ^ kg) & 3) << 3) + (fr & 7);
    pws1[j] = pw + r * 32 + ((((2 + (fr >> 3)) ^ kg) & 3) << 3) + (fr & 7);
  }
  const int rdswz = fr * 32 + (((kg ^ (fr >> 2)) & 3) << 3);

#define LOADK(kr0, kf) do {                                                    \
    const unsigned short* kp = kfB + (size_t)((kr0) >> 4) * 1024;              \
    kf[0] = ld8(kp);        kf[1] = ld8(kp + 512);                             \
    kf[2] = ld8(kp + 1024); kf[3] = ld8(kp + 1536);                            \
  } while (0)

#define LOADV(kr0, vf) do {                                                    \
    const unsigned short* vp = vfB + (size_t)((kr0) >> 5) * 2048;              \
    vf[0] = ld8(vp);        vf[1] = ld8(vp + 512);                             \
    vf[2] = ld8(vp + 1024); vf[3] = ld8(vp + 1536);                            \
  } while (0)

#define QKSM(kr0, kf, DOMASK) do {                                             \
    f32x4 s0 = zero4(), s1 = zero4();                                          \
    __builtin_amdgcn_s_setprio(1);                                             \
    s0 = __builtin_amdgcn_mfma_f32_16x16x32_bf16(qf0, kf[0], s0, 0, 0, 0);     \
    s0 = __builtin_amdgcn_mfma_f32_16x16x32_bf16(qf1, kf[1], s0, 0, 0, 0);     \
    s1 = __builtin_amdgcn_mfma_f32_16x16x32_bf16(qf0, kf[2], s1, 0, 0, 0);     \
    s1 = __builtin_amdgcn_mfma_f32_16x16x32_bf16(qf1, kf[3], s1, 0, 0, 0);     \
    __builtin_amdgcn_s_setprio(0);                                             \
    _Pragma("unroll")                                                          \
    for (int j = 0; j < 4; ++j) {                                              \
      float a0 = s0[j];                                                        \
      float a1 = s1[j];                                                        \
      if (DOMASK) {                                                            \
        const int qrow = qrow0 + kg * 4 + j;                                   \
        a0 = ((kr0) + fr      <= qrow) ? a0 : -1e30f;                          \
        a1 = ((kr0) + 16 + fr <= qrow) ? a1 : -1e30f;                          \
      }                                                                        \
      const float e0 = exp2f(a0);                                              \
      const float e1 = exp2f(a1);                                              \
      l_run[j] += e0 + e1;                                                     \
      *pws0[j] = f2bf(e0);                                                     \
      *pws1[j] = f2bf(e1);                                                     \
    }                                                                          \
  } while (0)

#define PV(vf) do {                                                            \
    __builtin_amdgcn_s_setprio(1);                                             \
    _Pragma("unroll")                                                          \
    for (int nd = 0; nd < 4; ++nd)                                             \
      o[nd] = __builtin_amdgcn_mfma_f32_16x16x32_bf16(pf, vf[nd], o[nd], 0, 0, 0); \
    __builtin_amdgcn_s_setprio(0);                                             \
  } while (0)

#define READP do { pf = ld8(pw + rdswz); } while (0)

  {
    const int qrow0 = qt * 64 + w * 16;
    const int nfull = qrow0 >> 5;       // fully-unmasked 32-k tiles; diagonal tile = nfull

    const unsigned short* qp = qb + (seq0 + qrow0 + fr) * 1024 + h * 64;
    const short8 qf0 = ld8(qp + kg * 8);
    const short8 qf1 = ld8(qp + 32 + kg * 8);

    float l_run[4] = {0.f, 0.f, 0.f, 0.f};
    f32x4 o[4];
    for (int n = 0; n < 4; ++n) o[n] = zero4();

    short8 kA[4], kB[4], vA[4], vB[4], pf;
    LOADK(0, kA);
    int kt = 0;
    while (true) {
      {   // even phase: K in kA; V(kt)->vA; PV(prev) from vB
        const int kn = (kt < nfull) ? (kt + 1) * 32 : nfull * 32;
        LOADK(kn, kB);
        LOADV(kt * 32, vA);
        if (kt == nfull) { QKSM(kt * 32, kA, 1); } else { QKSM(kt * 32, kA, 0); }
        if (kt > 0) PV(vB);
        READP;
      }
      if (kt == nfull) { PV(vA); break; }
      ++kt;
      {   // odd phase: K in kB; V(kt)->vB; PV(prev) from vA
        const int kn = (kt < nfull) ? (kt + 1) * 32 : nfull * 32;
        LOADK(kn, kA);
        LOADV(kt * 32, vB);
        if (kt == nfull) { QKSM(kt * 32, kB, 1); } else { QKSM(kt * 32, kB, 0); }
        PV(vA);
        READP;
      }
      if (kt == nfull) { PV(vB); break; }
      ++kt;
    }

    for (int j = 0; j < 4; ++j) {
      float l = l_run[j];
      l += __shfl_xor(l, 1);
      l += __shfl_xor(l, 2);
      l += __shfl_xor(l, 4);
      l += __shfl_xor(l, 8);
      const float inv = 1.0f / l;
      for (int nd = 0; nd < 4; ++nd) {
        om[(seq0 + qrow0 + kg * 4 + j) * 1024 + h * 64 + nd * 16 + fr] =
            f2bf(o[nd][j] * inv);
      }
    }
  }
#undef LOADK
#undef LOADV
#undef QKSM
#undef PV
#undef READP
}

// ---------------- launch ----------------
extern "C" void kernel_launch(void* const* d_in, const int* in_sizes, int n_in,
                              void* d_out, int out_size, void* d_ws, size_t ws_size,
                              hipStream_t stream) {
  const float* x    = (const float*)d_in[0];   // [2,2048,1024]
  const float* Wqkv = (const float*)d_in[1];   // [3072,1024]
  const float* Wout = (const float*)d_in[2];   // [1024,1024]
  float* out = (float*)d_out;                  // [2,2048,1024]

  char* ws = (char*)d_ws;
  unsigned short* xb    = (unsigned short*)(ws);                      //  8 MB  [4096][1024]
  unsigned short* wqkvb = (unsigned short*)(ws + 8388608);            //  6 MB  [3072][1024]
  unsigned short* woutb = (unsigned short*)(ws + 14680064);           //  2 MB  [1024][1024]
  unsigned short* qbuf  = (unsigned short*)(ws + 16777216);           //  8 MB  [4096][1024]
  unsigned short* kfb   = (unsigned short*)(ws + 25165824);           //  8 MB  fragment-linear K
  unsigned short* vfb   = (unsigned short*)(ws + 33554432);           //  8 MB  fragment-linear V
  unsigned short* attno = (unsigned short*)(ws + 41943040);           //  8 MB  [4096][1024]

  cvt3_kernel<<<dim3(8192), dim3(256), 0, stream>>>(
      (const float4*)x,    (ushort4*)xb,
      (const float4*)Wqkv, (ushort4*)wqkvb,
      (const float4*)Wout, (ushort4*)woutb);

  gemm_qkv<<<dim3(24, 32), dim3(256), 0, stream>>>(
      xb, wqkvb, (void*)qbuf, (void*)kfb, (void*)vfb, 4096, 3072, 1024);

  attn_kernel<<<dim3(32, 32), dim3(256), 0, stream>>>(qbuf, kfb, vfb, attno);

  gemm_out<<<dim3(8, 64), dim3(256), 0, stream>>>(attno, woutb, out, 4096, 1024, 1024);
}